// Round 5
// baseline (236.062 us; speedup 1.0000x reference)
//
#include <hip/hip_runtime.h>

// LocallyConnected2d: out[i,j] = sum_{kh,kw} x[i+kh, j+kw] * W[i,j,kh,kw]
// x: (450,450) f32 (810 KB, cache-resident), W: (436,436,15,15) f32 (171 MB,
// streamed exactly once) -> HBM-bound, floor ~= 171 MB / 6.9 TB/s ~= 25 us.
//
// R5 = R4 (wave-per-quad, stride-1 W loads, x via per-wave LDS patch) plus:
//  - TWO quads per wave, software-pipelined: issue q0 loads+staging, then q1
//    loads+staging, THEN compute q0, then q1. Doubles per-wave MLP; q1's
//    HBM latency hides under q0's compute/reduction.
//  - No __syncthreads: slabs are wave-private and per-wave DS ops execute
//    in order, so a zero-cost __builtin_amdgcn_wave_barrier() (compiler
//    reorder fence) replaces the full vmcnt(0)-drain block barrier.
//
// Compute core (verified R3/R4): element e = lane + 64t, segment s = e/225,
// boundary lanes per t are compile-time: t=3 lane33, t=7 lane2, t=10 lane35.

constexpr int IN_W = 450;
constexpr int OW = 436;
constexpr int NQUAD = (436 * 436) / 4;   // 47524
constexpr int HALF = NQUAD / 2;          // 23762

__device__ __forceinline__ void stage_patch(const float* __restrict__ x,
                                            float* __restrict__ lp,
                                            int lane, int xb0) {
#pragma unroll
    for (int p = 0; p < 5; ++p) {
        const int i = lane + 64 * p;     // 0..269 (p=4: lanes 0..13)
        if (p < 4 || i < 270) {
            const unsigned r = (unsigned)i / 18u;   // magic-mul
            const int c = i - (int)r * 18;
            lp[i] = x[xb0 + (int)r * IN_W + c];
        }
    }
}

__device__ __forceinline__ void compute_quad(const float* __restrict__ lp,
                                             const float wreg[14], float wtail,
                                             int lane, int o0,
                                             float* __restrict__ out) {
    constexpr int S0[14] = {0,0,0,0, 1,1,1,1, 2,2,2, 3,3,3};
    constexpr int BL[14] = {64,64,64,33, 64,64,64,2, 64,64,35, 64,64,64};
    constexpr int K0[14] = {0,64,128,192, 31,95,159,223, 62,126,190, 29,93,157};

    float acc[4] = {0.f, 0.f, 0.f, 0.f};
#pragma unroll
    for (int t = 0; t < 14; ++t) {
        const bool b = (BL[t] != 64) && (lane >= BL[t]);
        const unsigned k = (unsigned)(lane + K0[t] - (b ? 225 : 0)); // [0,225)
        const unsigned kh = k / 15u;                                 // magic-mul
        const int addr = (int)(k + 3u * kh) + S0[t] + (b ? 1 : 0);   // kh*18+kw+s
        const float pr = wreg[t] * lp[addr];
        if (BL[t] == 64) {
            acc[S0[t]] += pr;
        } else {
            if (b) acc[S0[t] + 1] += pr; else acc[S0[t]] += pr;
        }
    }
    if (lane < 4) acc[3] = fmaf(wtail, lp[266 + lane], acc[3]);

    // 14-shuffle reduction
#pragma unroll
    for (int a = 0; a < 4; ++a) acc[a] += __shfl_xor(acc[a], 32, 64);
    float zA = (lane < 32) ? acc[0] : acc[1];
    float zB = (lane < 32) ? acc[2] : acc[3];
#pragma unroll
    for (int off = 16; off > 0; off >>= 1) {
        zA += __shfl_xor(zA, off, 64);
        zB += __shfl_xor(zB, off, 64);
    }
    if (lane == 0)  { out[o0]     = zA; out[o0 + 2] = zB; }
    if (lane == 32) { out[o0 + 1] = zA; out[o0 + 3] = zB; }
}

__global__ __launch_bounds__(256)
void lc2d_quad2(const float* __restrict__ x,
                const float* __restrict__ W,
                float* __restrict__ out) {
    __shared__ float patch[4][2][270];   // two wave-private slabs per wave

    const int lane = threadIdx.x & 63;
    const int wv = threadIdx.x >> 6;
    const int w = blockIdx.x * 4 + wv;
    if (w >= HALF) return;               // last block: 2 idle waves

    const int q0 = w, q1 = w + HALF;

    // ---- quad 0: issue W loads + x staging ----
    const int oA = q0 * 4;
    const int oiA = oA / OW;
    const int xbA = oiA * IN_W + (oA - oiA * OW);
    const float* __restrict__ WqA = W + (size_t)oA * 225;

    float w0[14];
#pragma unroll
    for (int t = 0; t < 14; ++t) w0[t] = WqA[lane + 64 * t];
    float wt0 = (lane < 4) ? WqA[896 + lane] : 0.0f;
    stage_patch(x, patch[wv][0], lane, xbA);

    // ---- quad 1: issue W loads + x staging (prefetch) ----
    const int oB = q1 * 4;
    const int oiB = oB / OW;
    const int xbB = oiB * IN_W + (oB - oiB * OW);
    const float* __restrict__ WqB = W + (size_t)oB * 225;

    float w1[14];
#pragma unroll
    for (int t = 0; t < 14; ++t) w1[t] = WqB[lane + 64 * t];
    float wt1 = (lane < 4) ? WqB[896 + lane] : 0.0f;
    stage_patch(x, patch[wv][1], lane, xbB);

    __builtin_amdgcn_wave_barrier();     // fence: no read-before-write reorder

    // ---- compute both (q1's loads drain under q0's compute) ----
    compute_quad(patch[wv][0], w0, wt0, lane, oA, out);
    compute_quad(patch[wv][1], w1, wt1, lane, oB, out);
}

extern "C" void kernel_launch(void* const* d_in, const int* in_sizes, int n_in,
                              void* d_out, int out_size, void* d_ws, size_t ws_size,
                              hipStream_t stream) {
    const float* x = (const float*)d_in[0];  // (450,450)
    const float* W = (const float*)d_in[1];  // (436,436,15,15)
    float* out = (float*)d_out;              // (436,436)

    const int nblocks = (HALF + 3) / 4;      // 5941
    lc2d_quad2<<<nblocks, 256, 0, stream>>>(x, W, out);
}

// Round 6
// 235.100 us; speedup vs baseline: 1.0041x; 1.0041x over previous
//
#include <hip/hip_runtime.h>

// LocallyConnected2d: out[i,j] = sum_{kh,kw} x[i+kh, j+kw] * W[i,j,kh,kw]
// x: (450,450) f32 (810 KB, cache-resident), W: (436,436,15,15) f32 (171 MB,
// streamed exactly once) -> HBM-bound, floor ~= 171 MB / 6.9 TB/s ~= 25 us.
//
// R6 = R3's wide W loads + R4's LDS x patch (each verified separately):
//  - W: one quad (4 consecutive outputs) = 900 contiguous floats = 225
//    float4s, 16B-aligned. Lane l loads global_load_dwordx4 at l+64t,
//    t=0..2 full + t=3 on lanes 0..32. 4 VMEM instructions for the whole
//    3600 B quad payload (vs 15 scalar-dword in R4) -> TA/issue pressure
//    per quad drops 20 -> 9 VMEM instructions.
//  - x: staged once per wave into a wave-private 15x18 LDS patch (5 VMEM),
//    then read stride-pattern ds_read_b32, conflict-free-ish (<=2-way).
//  - Element e = 4*lane + 256*t + c; segment s = t + b where
//    b = (4*lane+c >= 225-31*t); k = 4*lane+c+31*t-225*b;
//    LDS addr = k + 3*(k/15) + s  (= kh*18+kw+s).
//  - 14-shuffle packed reduction (R4), float stores via lanes 0/32.

constexpr int IN_W = 450;
constexpr int OW = 436;
constexpr int NQUAD = (436 * 436) / 4;   // 47524 = 11881 blocks * 4 waves

__global__ __launch_bounds__(256)
void lc2d_x4_lds(const float* __restrict__ x,
                 const float* __restrict__ W,
                 float* __restrict__ out) {
    __shared__ float patch[4][270];      // per-wave 15x18 slab

    const int lane = threadIdx.x & 63;
    const int wid = threadIdx.x >> 6;
    const int q = blockIdx.x * 4 + wid;  // grid exact, no bounds check

    const int o0 = q * 4;
    const int oi = o0 / OW;              // magic-mul
    const int oj = o0 - oi * OW;         // multiple of 4 -> no row wrap
    const int xb0 = oi * IN_W + oj;

    const float4* __restrict__ W4 = (const float4*)W + (size_t)q * 225;

    // ---- W loads first: the HBM long pole, 4 wide instructions ----
    float4 wq0 = W4[lane];
    float4 wq1 = W4[lane + 64];
    float4 wq2 = W4[lane + 128];
    float4 wq3 = make_float4(0.f, 0.f, 0.f, 0.f);
    if (lane < 33) wq3 = W4[lane + 192];        // elements 768..899

    // ---- stage x patch 15x18 into this wave's slab (5 VMEM) ----
    float* lp = patch[wid];
#pragma unroll
    for (int p = 0; p < 5; ++p) {
        const int i = lane + 64 * p;            // 0..269 (p=4: lanes 0..13)
        if (p < 4 || i < 270) {
            const unsigned r = (unsigned)i / 18u;   // magic-mul
            const int c = i - (int)r * 18;
            lp[i] = x[xb0 + (int)r * IN_W + c];
        }
    }
    __builtin_amdgcn_wave_barrier();  // slab is wave-private; DS ops in-order

    float acc[4] = {0.f, 0.f, 0.f, 0.f};
    const int el4 = lane * 4;

    // t = 0,1,2: all lanes active
    {
        const float4 wqs[3] = {wq0, wq1, wq2};
#pragma unroll
        for (int t = 0; t < 3; ++t) {
            const float wv4[4] = {wqs[t].x, wqs[t].y, wqs[t].z, wqs[t].w};
#pragma unroll
            for (int c = 0; c < 4; ++c) {
                const bool b = (el4 + c) >= (225 - 31 * t);
                const unsigned k = (unsigned)(el4 + c + 31 * t - (b ? 225 : 0));
                const unsigned kh = k / 15u;            // magic-mul
                const int addr = (int)(k + 3u * kh) + t + (b ? 1 : 0);
                const float pr = wv4[c] * lp[addr];
                if (b) acc[t + 1] += pr; else acc[t] += pr;  // static indices
            }
        }
    }
    // t = 3: lanes 0..32, elements 768..899, all segment 3
    if (lane < 33) {
        const float wv4[4] = {wq3.x, wq3.y, wq3.z, wq3.w};
#pragma unroll
        for (int c = 0; c < 4; ++c) {
            const unsigned k = (unsigned)(el4 + c + 93);   // 93..224
            const unsigned kh = k / 15u;
            const int addr = (int)(k + 3u * kh) + 3;
            acc[3] = fmaf(wv4[c], lp[addr], acc[3]);
        }
    }

    // ---- 14-shuffle reduction ----
#pragma unroll
    for (int a = 0; a < 4; ++a) acc[a] += __shfl_xor(acc[a], 32, 64);
    float zA = (lane < 32) ? acc[0] : acc[1];
    float zB = (lane < 32) ? acc[2] : acc[3];
#pragma unroll
    for (int off = 16; off > 0; off >>= 1) {
        zA += __shfl_xor(zA, off, 64);
        zB += __shfl_xor(zB, off, 64);
    }
    if (lane == 0)  { out[o0]     = zA; out[o0 + 2] = zB; }
    if (lane == 32) { out[o0 + 1] = zA; out[o0 + 3] = zB; }
}

extern "C" void kernel_launch(void* const* d_in, const int* in_sizes, int n_in,
                              void* d_out, int out_size, void* d_ws, size_t ws_size,
                              hipStream_t stream) {
    const float* x = (const float*)d_in[0];  // (450,450)
    const float* W = (const float*)d_in[1];  // (436,436,15,15)
    float* out = (float*)d_out;              // (436,436)

    const int nblocks = NQUAD / 4;           // 11881, exact
    lc2d_x4_lds<<<nblocks, 256, 0, stream>>>(x, W, out);
}